// Round 4
// baseline (321.755 us; speedup 1.0000x reference)
//
#include <hip/hip_runtime.h>
#include <math.h>

#define M_SPATIAL 2097152  // 128^3

__device__ __forceinline__ float wave_redf(float v) {
#pragma unroll
  for (int o = 32; o > 0; o >>= 1) v += __shfl_down(v, o, 64);
  return v;
}
__device__ __forceinline__ double wave_redd(double v) {
#pragma unroll
  for (int o = 32; o > 0; o >>= 1) v += __shfl_down(v, o, 64);
  return v;
}

// part layout (doubles), 512 blocks per producing kernel:
// [0..511]=ce  [512..1023]=p  [1024..1535]=pt  [1536..2047]=t  [2048..2559]=dist
// blocks 0..255 -> b=0, 256..511 -> b=1.

// ---------------------------------------------------------------------------
// k1: fused CE/dice partials + X-axis EDT of the binary mask (two int scans).
// Lines along x (stride 16384); lane owns one line; 64 lines/block.
// g out: int32, exact ( m^2 if bg exists in line else 1e6 ).
// ---------------------------------------------------------------------------
__global__ __launch_bounds__(64) void k1_init_x(const float* __restrict__ outputs,
                                                const int* __restrict__ y,
                                                int* __restrict__ g,
                                                double* __restrict__ part) {
  __shared__ int df[128 * 64];
  int blk = blockIdx.x;            // b*256 + yy*2 + zc
  int b  = blk >> 8;
  int yy = (blk >> 1) & 127;
  int zc = blk & 1;
  int l  = threadIdx.x;
  size_t sp   = (size_t)yy * 128 + (size_t)zc * 64 + l;   // spatial offset in volume
  size_t base = (size_t)b * M_SPATIAL + sp;               // for y and g (b-indexed)
  const float* xc = outputs + (size_t)(2 * b + 1) * M_SPATIAL;  // channel-1 logits

  float ce = 0.f, ps = 0.f, pts = 0.f, ts = 0.f;
  int d = 200;
  for (int u0 = 0; u0 < 128; u0 += 16) {
    int   yb[16];
    float xb[16];
#pragma unroll
    for (int k = 0; k < 16; ++k) {
      size_t off = (size_t)(u0 + k) * 16384;
      yb[k] = y[base + off];
      xb[k] = xc[sp + off];        // FIX: spatial-only index for outputs
    }
#pragma unroll
    for (int k = 0; k < 16; ++k) {
      int fg = (yb[k] == 1);
      float t = fg ? 1.f : 0.f;
      d = fg ? ((d < 200) ? d + 1 : 200) : 0;
      df[(u0 + k) * 64 + l] = d;
      float xx = xb[k];
      ce += fmaxf(xx, 0.f) - xx * t + log1pf(expf(-fabsf(xx)));
      float p = 1.f / (1.f + expf(-xx));
      ps += p; pts += p * t; ts += t;
    }
  }
  int db = 200;
  for (int u0 = 127; u0 >= 0; u0 -= 16) {
    int dfv[16];
#pragma unroll
    for (int k = 0; k < 16; ++k) dfv[k] = df[(u0 - k) * 64 + l];
#pragma unroll
    for (int k = 0; k < 16; ++k) {
      int u = u0 - k;
      int fv = dfv[k];
      db = (fv > 0) ? ((db < 200) ? db + 1 : 200) : 0;
      int m = min(fv, db);
      g[base + (size_t)u * 16384] = (m >= 128) ? 1000000 : m * m;
    }
  }
  float r0 = wave_redf(ce), r1 = wave_redf(ps), r2 = wave_redf(pts), r3 = wave_redf(ts);
  if (l == 0) {
    part[blk]        = (double)r0;
    part[512 + blk]  = (double)r1;
    part[1024 + blk] = (double)r2;
    part[1536 + blk] = (double)r3;
  }
}

// ---------------------------------------------------------------------------
// Meijster exact 1D squared-EDT construction (integer arithmetic, O(n)).
// Per-lane: stack window (top, second) in registers; deeper entries in LDS.
// gl column addressing: GI(z) = z*64 + ((l + SWZ*z) & 63)  (lane-owned column).
// All values < 2^21 -> float-division Sep with floor fixup is exact.
// ---------------------------------------------------------------------------
template <int SWZ>
__device__ __forceinline__ void meijster_build(const int* gl, unsigned short* stk,
                                               int l, int& q, int& s0, int& t0, int& g0,
                                               int& s1, int& t1, int& g1) {
#define GI(z) ((z) * 64 + ((l + SWZ * (z)) & 63))
  q = 0; s0 = 0; t0 = 0; g0 = gl[GI(0)];
  s1 = 0; t1 = 0; g1 = 0;
  for (int ub = 0; ub < 128; ub += 8) {
    int gub[8];
#pragma unroll
    for (int k = 0; k < 8; ++k) gub[k] = gl[GI(ub + k)];
#pragma unroll
    for (int k = 0; k < 8; ++k) {
      int u = ub + k;
      if (u == 0) continue;           // only first batch
      int gu = gub[k];
      for (;;) {                       // pop loop
        if (q < 0) break;
        int a1 = t0 - s0, a2 = t0 - u;
        if (a1 * a1 + g0 > a2 * a2 + gu) {
          q--;
          if (q >= 0) {
            s0 = s1; t0 = t1; g0 = g1;
            if (q >= 1) {
              unsigned short v = stk[(q - 1) * 64 + l];
              s1 = v & 255; t1 = v >> 8;
              g1 = gl[GI(s1)];
            }
          }
        } else break;
      }
      if (q < 0) { q = 0; s0 = u; t0 = 0; g0 = gu; }
      else {
        int num = u * u - s0 * s0 + gu - g0;   // |num| < 2^21 -> exact in float
        int den = 2 * (u - s0);
        int w = (int)((float)num / (float)den);
        w -= (w * den > num);
        w += ((w + 1) * den <= num);
        w += 1;
        if (w < 128) {
          if (q >= 1) stk[(q - 1) * 64 + l] = (unsigned short)(s1 | (t1 << 8));
          s1 = s0; t1 = t0; g1 = g0;
          s0 = u; t0 = w; g0 = gu;
          q++;
        }
      }
    }
  }
#undef GI
}

// ---------------------------------------------------------------------------
// k2: Y-axis EDT (stride-128 lines). Coalesced stage-in/out; int32 g.
// ---------------------------------------------------------------------------
__global__ __launch_bounds__(64) void k2_edt_y(int* __restrict__ g) {
  __shared__ int gl[128 * 64];
  __shared__ unsigned short stk[128 * 64];
  int blk = blockIdx.x;            // b*256 + x*2 + zc
  int b = blk >> 8, xx = (blk >> 1) & 127, zc = blk & 1;
  int l = threadIdx.x;
  size_t base = (size_t)b * M_SPATIAL + (size_t)xx * 16384 + (size_t)zc * 64 + l;
#pragma unroll 16
  for (int u = 0; u < 128; ++u) gl[u * 64 + l] = g[base + (size_t)u * 128];

  int q, s0, t0, g0, s1, t1, g1;
  meijster_build<0>(gl, stk, l, q, s0, t0, g0, s1, t1, g1);

  for (int u = 127; u >= 0; --u) {
    int dv = (u - s0) * (u - s0) + g0;
    g[base + (size_t)u * 128] = dv;
    if (u == t0 && q > 0) {
      q--;
      s0 = s1; t0 = t1; g0 = g1;
      if (q >= 1) {
        unsigned short v = stk[(q - 1) * 64 + l];
        s1 = v & 255; t1 = v >> 8;
        g1 = gl[s1 * 64 + l];
      }
    }
  }
}

// ---------------------------------------------------------------------------
// k3: Z-axis EDT (contiguous lines, swizzled LDS transpose) fused with the
// dist-loss partial: sum |od - sqrt(d)| over d>0. No g write-back.
// ---------------------------------------------------------------------------
__global__ __launch_bounds__(64) void k3_edt_z_dist(const int* __restrict__ g,
                                                    const float* __restrict__ od,
                                                    double* __restrict__ part) {
  __shared__ int gl[128 * 64];
  __shared__ unsigned short stk[128 * 64];
  int blk = blockIdx.x;            // b*256 + x*2 + yc
  int b = blk >> 8, xx = (blk >> 1) & 127, yc = blk & 1;
  int l = threadIdx.x;
  size_t B0 = (size_t)b * M_SPATIAL + (size_t)xx * 16384 + (size_t)yc * 8192;
  size_t OC = (size_t)(2 * b + 1) * M_SPATIAL + (size_t)xx * 16384 + (size_t)yc * 8192;

  // Prefetch this lane's whole od line (128 floats) into registers up front;
  // latency hidden behind staging + construction.
  const float4* od4 = (const float4*)od;
  size_t ob4 = (OC >> 2) + (size_t)l * 32;
  float4 A[32];
#pragma unroll
  for (int k = 0; k < 32; ++k) A[k] = od4[ob4 + k];

  // Swizzled coalesced stage-in: gl[z*64 + ((line+z)&63)]
#pragma unroll 16
  for (int k = 0; k < 128; ++k) {
    int L = k >> 1;
    int z = ((k & 1) << 6) + l;
    gl[z * 64 + ((L + z) & 63)] = g[B0 + (size_t)L * 128 + z];
  }
  __syncthreads();

  int q, s0, t0, g0, s1, t1, g1;
  meijster_build<1>(gl, stk, l, q, s0, t0, g0, s1, t1, g1);

  const float* af = (const float*)A;
  float dist = 0.f;
#pragma unroll
  for (int j = 0; j < 128; ++j) {
    int u = 127 - j;
    int dv = (u - s0) * (u - s0) + g0;
    if (dv > 0) dist += fabsf(af[u] - sqrtf((float)dv));
    if (u == t0 && q > 0) {
      q--;
      s0 = s1; t0 = t1; g0 = g1;
      if (q >= 1) {
        unsigned short v = stk[(q - 1) * 64 + l];
        s1 = v & 255; t1 = v >> 8;
        g1 = gl[s1 * 64 + ((l + s1) & 63)];
      }
    }
  }
  float r = wave_redf(dist);
  if (l == 0) part[2048 + blk] = (double)r;
}

// ---------------------------------------------------------------------------
// k_final: reduce 5x512 partials, combine to scalar loss.
// ---------------------------------------------------------------------------
__global__ __launch_bounds__(256) void k_final(const double* __restrict__ part,
                                               const float* __restrict__ wptr,
                                               float* __restrict__ out) {
  int i = threadIdx.x;
  double ce  = part[i] + part[256 + i];
  double p0  = part[512 + i],  p1  = part[768 + i];
  double pt0 = part[1024 + i], pt1 = part[1280 + i];
  double t0  = part[1536 + i], t1  = part[1792 + i];
  double ds  = part[2048 + i] + part[2304 + i];

  ce = wave_redd(ce); p0 = wave_redd(p0); p1 = wave_redd(p1);
  pt0 = wave_redd(pt0); pt1 = wave_redd(pt1);
  t0 = wave_redd(t0); t1 = wave_redd(t1); ds = wave_redd(ds);

  __shared__ double sm[4][8];
  int lane = threadIdx.x & 63, w = threadIdx.x >> 6;
  if (lane == 0) {
    sm[w][0] = ce; sm[w][1] = p0; sm[w][2] = p1; sm[w][3] = pt0;
    sm[w][4] = pt1; sm[w][5] = t0; sm[w][6] = t1; sm[w][7] = ds;
  }
  __syncthreads();
  if (threadIdx.x == 0) {
    double a[8];
    for (int qd = 0; qd < 8; ++qd) a[qd] = sm[0][qd] + sm[1][qd] + sm[2][qd] + sm[3][qd];
    double cem = a[0] / 4194304.0;
    double dice0 = (2.0 * a[3] + 1.0) / (a[1] + a[5] + 1.0);
    double dice1 = (2.0 * a[4] + 1.0) / (a[2] + a[6] + 1.0);
    double ldice = 1.0 - 0.5 * (dice0 + dice1);
    double msum = a[5] + a[6];
    double ldist = (msum == 0.0) ? 0.0 : a[7] / fmax(msum, 1e-12);
    out[0] = (float)(cem + ldice + (double)wptr[0] * ldist);
  }
}

extern "C" void kernel_launch(void* const* d_in, const int* in_sizes, int n_in,
                              void* d_out, int out_size, void* d_ws, size_t ws_size,
                              hipStream_t stream) {
  const float* outputs      = (const float*)d_in[0];
  const float* outputs_dist = (const float*)d_in[1];
  const int*   y            = (const int*)d_in[2];
  const float* wptr         = (const float*)d_in[3];
  float* out = (float*)d_out;

  double* part = (double*)d_ws;                    // 2560 doubles = 20 KiB
  int* g = (int*)((char*)d_ws + 65536);            // 16 MiB int32 field

  k1_init_x<<<512, 64, 0, stream>>>(outputs, y, g, part);
  k2_edt_y<<<512, 64, 0, stream>>>(g);
  k3_edt_z_dist<<<512, 64, 0, stream>>>(g, outputs_dist, part);
  k_final<<<1, 256, 0, stream>>>(part, wptr, out);
}

// Round 5
// 171.790 us; speedup vs baseline: 1.8730x; 1.8730x over previous
//
#include <hip/hip_runtime.h>
#include <math.h>

#define M_SPATIAL 2097152  // 128^3
#define MV4 (M_SPATIAL / 4)

__device__ __forceinline__ float wave_redf(float v) {
#pragma unroll
  for (int o = 32; o > 0; o >>= 1) v += __shfl_down(v, o, 64);
  return v;
}
__device__ __forceinline__ double wave_redd(double v) {
#pragma unroll
  for (int o = 32; o > 0; o >>= 1) v += __shfl_down(v, o, 64);
  return v;
}

// part layout (doubles):
// [0..1023]=ce  [1024..2047]=p  [2048..3071]=pt  [3072..4095]=t  [4096..5119]=dist
// kA blocks 0..511 -> b=0, 512..1023 -> b=1 (same for kD's blk>>9).

// ---------------------------------------------------------------------------
// kA: streaming CE + dice partials (float4/int4, per-block slots, no atomics).
// ---------------------------------------------------------------------------
__global__ __launch_bounds__(256) void kA_ce(const float4* __restrict__ outputs4,
                                             const int4* __restrict__ y4,
                                             double* __restrict__ part) {
  int blk = blockIdx.x;                 // 0..1023
  int base = blk * 1024;                // vec4 slots
  int b = (blk >= 512) ? 1 : 0;
  const float4* xc = outputs4 + (size_t)(b * 2 + 1) * MV4;
  float ce = 0.f, ps = 0.f, pts = 0.f, tsum = 0.f;
#pragma unroll
  for (int k = 0; k < 4; ++k) {
    int v4 = base + (int)threadIdx.x + k * 256;
    int s4 = v4 & (MV4 - 1);
    int4 yv = y4[v4];
    float4 x = xc[s4];
#define ELEM(c, yc)                                                         \
    {                                                                       \
      float t = (yc == 1) ? 1.0f : 0.0f;                                    \
      float xx = x.c;                                                       \
      ce += fmaxf(xx, 0.0f) - xx * t + log1pf(expf(-fabsf(xx)));            \
      float p = 1.0f / (1.0f + expf(-xx));                                  \
      ps += p; pts += p * t; tsum += t;                                     \
    }
    ELEM(x, yv.x) ELEM(y, yv.y) ELEM(z, yv.z) ELEM(w, yv.w)
#undef ELEM
  }
  float r0 = wave_redf(ce), r1 = wave_redf(ps), r2 = wave_redf(pts), r3 = wave_redf(tsum);
  __shared__ float sm[4][4];
  int lane = threadIdx.x & 63, w = threadIdx.x >> 6;
  if (lane == 0) { sm[w][0] = r0; sm[w][1] = r1; sm[w][2] = r2; sm[w][3] = r3; }
  __syncthreads();
  if (threadIdx.x == 0) {
    part[blk]        = (double)(sm[0][0] + sm[1][0] + sm[2][0] + sm[3][0]);
    part[1024 + blk] = (double)(sm[0][1] + sm[1][1] + sm[2][1] + sm[3][1]);
    part[2048 + blk] = (double)(sm[0][2] + sm[1][2] + sm[2][2] + sm[3][2]);
    part[3072 + blk] = (double)(sm[0][3] + sm[1][3] + sm[2][3] + sm[3][3]);
  }
}

// ---------------------------------------------------------------------------
// kB: X-axis EDT of the binary mask via two O(n) integer scans (branch-free),
// writing h = gX + y^2 as float (1e6 + y^2 when no bg in the line).
// Lane owns one x-line; df column in LDS is lane-private (no syncthreads).
// ---------------------------------------------------------------------------
__global__ __launch_bounds__(64) void kB_edtx(const int* __restrict__ y,
                                              float* __restrict__ g) {
  __shared__ int df[128 * 64];
  int blk = blockIdx.x;            // b*256 + yy*2 + zc
  int b  = blk >> 8;
  int yy = (blk >> 1) & 127;
  int zc = blk & 1;
  int l  = threadIdx.x;
  size_t base = (size_t)b * M_SPATIAL + (size_t)yy * 128 + (size_t)zc * 64 + l;

  int d = 200;
  for (int u0 = 0; u0 < 128; u0 += 16) {
    int yb[16];
#pragma unroll
    for (int k = 0; k < 16; ++k) yb[k] = y[base + (size_t)(u0 + k) * 16384];
#pragma unroll
    for (int k = 0; k < 16; ++k) {
      int fg = (yb[k] == 1);
      d = fg ? ((d < 200) ? d + 1 : 200) : 0;
      df[(u0 + k) * 64 + l] = d;
    }
  }
  float hinf = 1000000.f + (float)(yy * yy);
  float yy2f = (float)(yy * yy);
  int db = 200;
  for (int u0 = 127; u0 >= 0; u0 -= 16) {
    int fv[16];
#pragma unroll
    for (int k = 0; k < 16; ++k) fv[k] = df[(u0 - k) * 64 + l];
    float ov[16];
#pragma unroll
    for (int k = 0; k < 16; ++k) {
      db = (fv[k] > 0) ? ((db < 200) ? db + 1 : 200) : 0;
      int m = min(fv[k], db);
      ov[k] = (m >= 128) ? hinf : ((float)(m * m) + yy2f);
    }
#pragma unroll
    for (int k = 0; k < 16; ++k) g[base + (size_t)(u0 - k) * 16384] = ov[k];
  }
}

// ---------------------------------------------------------------------------
// kC: Y-axis pass, 2-op inner loop. In-place on g (per-block element sets are
// disjoint). Block = (b, x, 32-z chunk); thread: fixed z, 16 contiguous i(=y).
// Writes h' = dY + z^2 for the Z pass. All values exact ints < 2^21 in fp32.
// ---------------------------------------------------------------------------
__global__ __launch_bounds__(256) void kC_edty(float* __restrict__ g) {
  __shared__ float hl[128 * 33];   // hl[j*33 + zl]
  int blk = blockIdx.x;            // b*512 + xx*4 + zc
  int b = blk >> 9, xx = (blk >> 2) & 127, zc = blk & 3;
  int t = threadIdx.x;
  size_t rb = (size_t)b * M_SPATIAL + (size_t)xx * 16384 + (size_t)zc * 32;

  // Stage 128 rows x 32 z (float4, coalesced; LDS 2-way at most = free).
#pragma unroll
  for (int r = 0; r < 4; ++r) {
    int i4 = t + r * 256;          // 0..1023 float4 units
    int j = i4 >> 3, w = i4 & 7;   // row j, 4*w z-offset
    float4 v = *(const float4*)(g + rb + (size_t)j * 128 + 4 * w);
    hl[j * 33 + 4 * w + 0] = v.x;
    hl[j * 33 + 4 * w + 1] = v.y;
    hl[j * 33 + 4 * w + 2] = v.z;
    hl[j * 33 + 4 * w + 3] = v.w;
  }
  __syncthreads();

  int zl = t & 31, ig = t >> 5;
  float best[16], mc[16];
#pragma unroll
  for (int k = 0; k < 16; ++k) {
    best[k] = 3.0e38f;
    mc[k] = -2.0f * (float)(ig * 16 + k);
  }
#pragma unroll 4
  for (int j = 0; j < 128; ++j) {
    float hj = hl[j * 33 + zl];
    float jf = (float)j;
#pragma unroll
    for (int k = 0; k < 16; ++k) best[k] = fminf(best[k], fmaf(mc[k], jf, hj));
  }
  int gz = zc * 32 + zl;
  float zq = (float)(gz * gz);
  size_t ob = rb + zl;
#pragma unroll
  for (int k = 0; k < 16; ++k) {
    int i = ig * 16 + k;
    float dY = (float)(i * i) + best[k];   // exact int
    g[ob + (size_t)i * 128] = dY + zq;     // h for Z pass
  }
}

// ---------------------------------------------------------------------------
// kD: Z-axis pass (contiguous lines) + fused dist-loss partial.
// Block = (b, x, 32-y chunk): 4096 contiguous floats staged via LDS transpose.
// Thread: fixed y-line, 16 contiguous i(=z) -> od read as coalesced float4.
// ---------------------------------------------------------------------------
__global__ __launch_bounds__(256) void kD_edtz_dist(const float* __restrict__ g,
                                                    const float* __restrict__ od,
                                                    double* __restrict__ part) {
  __shared__ float hl[128 * 33];   // hl[z*33 + yl]
  __shared__ float sred[4];
  int blk = blockIdx.x;            // b*512 + xx*4 + yc
  int b = blk >> 9, xx = (blk >> 2) & 127, yc = blk & 3;
  int t = threadIdx.x;
  size_t rb = (size_t)b * M_SPATIAL + (size_t)xx * 16384 + (size_t)yc * 4096;
  int yl = t & 31, ig = t >> 5;

  // Prefetch od (this thread's 16 consecutive z) early to hide latency.
  size_t odb = (size_t)(2 * b + 1) * M_SPATIAL + (size_t)xx * 16384 +
               (size_t)yc * 4096 + (size_t)yl * 128 + (size_t)ig * 16;
  const float4* o4 = (const float4*)(od + odb);
  float4 ov[4];
#pragma unroll
  for (int r = 0; r < 4; ++r) ov[r] = o4[r];

  const float4* h4 = (const float4*)(g + rb);
#pragma unroll
  for (int r = 0; r < 4; ++r) {
    int i4 = t + r * 256;
    float4 v = h4[i4];
    int flat = i4 * 4;
    int z = flat & 127, yw = flat >> 7;  // z%4==0, all 4 comps same yw
    hl[(z + 0) * 33 + yw] = v.x;
    hl[(z + 1) * 33 + yw] = v.y;
    hl[(z + 2) * 33 + yw] = v.z;
    hl[(z + 3) * 33 + yw] = v.w;
  }
  __syncthreads();

  float best[16], mc[16];
#pragma unroll
  for (int k = 0; k < 16; ++k) {
    best[k] = 3.0e38f;
    mc[k] = -2.0f * (float)(ig * 16 + k);
  }
#pragma unroll 4
  for (int j = 0; j < 128; ++j) {
    float hj = hl[j * 33 + yl];
    float jf = (float)j;
#pragma unroll
    for (int k = 0; k < 16; ++k) best[k] = fminf(best[k], fmaf(mc[k], jf, hj));
  }
  const float* of = (const float*)ov;
  float dist = 0.f;
#pragma unroll
  for (int k = 0; k < 16; ++k) {
    int i = ig * 16 + k;
    float dv = (float)(i * i) + best[k];   // exact squared EDT
    if (dv > 0.f) dist += fabsf(of[k] - sqrtf(dv));
  }
  float r = wave_redf(dist);
  int lane = t & 63, w = t >> 6;
  if (lane == 0) sred[w] = r;
  __syncthreads();
  if (t == 0) part[4096 + blk] = (double)(sred[0] + sred[1] + sred[2] + sred[3]);
}

// ---------------------------------------------------------------------------
// k_final: reduce 5x1024 partials, combine to scalar loss.
// ---------------------------------------------------------------------------
__global__ __launch_bounds__(256) void k_final(const double* __restrict__ part,
                                               const float* __restrict__ wptr,
                                               float* __restrict__ out) {
  int i = threadIdx.x;
  double ce  = part[i] + part[i + 256] + part[i + 512] + part[i + 768];
  double p0  = part[1024 + i] + part[1024 + i + 256];
  double p1  = part[1536 + i] + part[1536 + i + 256];
  double pt0 = part[2048 + i] + part[2048 + i + 256];
  double pt1 = part[2560 + i] + part[2560 + i + 256];
  double t0  = part[3072 + i] + part[3072 + i + 256];
  double t1  = part[3584 + i] + part[3584 + i + 256];
  double ds  = part[4096 + i] + part[4096 + i + 256] + part[4096 + i + 512] + part[4096 + i + 768];

  ce = wave_redd(ce); p0 = wave_redd(p0); p1 = wave_redd(p1);
  pt0 = wave_redd(pt0); pt1 = wave_redd(pt1);
  t0 = wave_redd(t0); t1 = wave_redd(t1); ds = wave_redd(ds);

  __shared__ double sm[4][8];
  int lane = threadIdx.x & 63, w = threadIdx.x >> 6;
  if (lane == 0) {
    sm[w][0] = ce; sm[w][1] = p0; sm[w][2] = p1; sm[w][3] = pt0;
    sm[w][4] = pt1; sm[w][5] = t0; sm[w][6] = t1; sm[w][7] = ds;
  }
  __syncthreads();
  if (threadIdx.x == 0) {
    double a[8];
    for (int q = 0; q < 8; ++q) a[q] = sm[0][q] + sm[1][q] + sm[2][q] + sm[3][q];
    double cem = a[0] / 4194304.0;
    double dice0 = (2.0 * a[3] + 1.0) / (a[1] + a[5] + 1.0);
    double dice1 = (2.0 * a[4] + 1.0) / (a[2] + a[6] + 1.0);
    double ldice = 1.0 - 0.5 * (dice0 + dice1);
    double msum = a[5] + a[6];
    double ldist = (msum == 0.0) ? 0.0 : a[7] / fmax(msum, 1e-12);
    out[0] = (float)(cem + ldice + (double)wptr[0] * ldist);
  }
}

extern "C" void kernel_launch(void* const* d_in, const int* in_sizes, int n_in,
                              void* d_out, int out_size, void* d_ws, size_t ws_size,
                              hipStream_t stream) {
  const float* outputs      = (const float*)d_in[0];
  const float* outputs_dist = (const float*)d_in[1];
  const int*   y            = (const int*)d_in[2];
  const float* wptr         = (const float*)d_in[3];
  float* out = (float*)d_out;

  double* part = (double*)d_ws;                    // 5120 doubles = 40 KiB
  float* g = (float*)((char*)d_ws + 65536);        // 16 MiB h/g field

  kA_ce<<<1024, 256, 0, stream>>>((const float4*)outputs, (const int4*)y, part);
  kB_edtx<<<512, 64, 0, stream>>>(y, g);           // X scan -> h = gX + y^2
  kC_edty<<<1024, 256, 0, stream>>>(g);            // Y pass -> h = dY + z^2
  kD_edtz_dist<<<1024, 256, 0, stream>>>(g, outputs_dist, part);  // Z + dist
  k_final<<<1, 256, 0, stream>>>(part, wptr, out);
}